// Round 5
// baseline (222.555 us; speedup 1.0000x reference)
//
#include <hip/hip_runtime.h>
#include <hip/hip_bf16.h>

typedef __attribute__((ext_vector_type(4))) float f32x4;
typedef __attribute__((ext_vector_type(8))) short bf16x8;
typedef __attribute__((ext_vector_type(4))) short s16x4;

#define C_IN   64
#define HW_IN  64
#define D_OUT  512
#define K_TOT  4096

// A window: 36 rows x 72 (stride) bf16; valid interior cols 2..65, rest zero.
#define AROWS 36
#define ASTR  72

__device__ __forceinline__ short f2bf(float x) {
    __hip_bfloat16 h = __float2bfloat16(x);
    return __builtin_bit_cast(short, h);
}
__device__ __forceinline__ uint pk2(float a, float b) {
    return (uint)(ushort)f2bf(a) | ((uint)(ushort)f2bf(b) << 16);
}

// ---------------- kernel 0: W f32 -> bf16 (N x K row-major) ----------------
__global__ void wcvt_kernel(const float* __restrict__ W, ushort* __restrict__ Wb) {
    int i = (blockIdx.x * 256 + threadIdx.x) * 4;
    if (i < D_OUT * K_TOT) {
        f32x4 v = *(const f32x4*)(W + i);
        s16x4 o;
        o[0] = f2bf(v[0]); o[1] = f2bf(v[1]); o[2] = f2bf(v[2]); o[3] = f2bf(v[3]);
        *(s16x4*)(Wb + i) = o;
    }
}

// ---------------- kernel 1: implicit-GEMM conv + bias + pos-enc ----------------
// Grid: 512 = 128 M-tiles (BM=128 tokens) x 4 N-tiles (BN=128 of D).
// Block: 256 threads = 4 waves (2x2), each wave a 64x64 sub-tile.
// A: f32 global -> bf16 LDS (double-buffered, depth-2 reg prefetch).
// B: bf16 global (L2-resident W slice) -> registers directly, depth-1 dbuf.
// XCD-chunked bid swizzle keeps one 1MB W-slice per XCD L2.
__global__ __launch_bounds__(256) void tok_gemm(
    const float* __restrict__ fm,     // (64, 64, 64, 64) f32
    const ushort* __restrict__ Wb,    // (512, 4096) bf16
    const float* __restrict__ bias,   // (512)
    float* __restrict__ out)          // (64, 256, 512) f32
{
    __shared__ __align__(16) ushort As[2][AROWS * ASTR];   // bf16 channel window

    // XCD swizzle: raw&7 = hw XCD; give each XCD a contiguous 64-block chunk
    const int raw   = blockIdx.x;
    const int bid   = (raw & 7) * 64 + (raw >> 3);   // bijective, 512 = 8*64
    const int mtile = bid & 127;
    const int ntile = bid >> 7;                      // constant per XCD-pair

    const int bb   = mtile >> 1;     // batch image
    const int half = mtile & 1;      // top/bottom 8 token rows

    const int tid  = threadIdx.x;
    const int lane = tid & 63;
    const int wid  = tid >> 6;
    const int wr   = wid >> 1;
    const int wc   = wid & 1;
    const int l15  = lane & 15;
    const int l4   = lane >> 4;

    // ---- zero-init A buffers once (pad cols + invalid rows stay 0 forever)
    for (int i = tid; i < 2 * AROWS * ASTR / 4; i += 256)
        ((unsigned long long*)As)[i] = 0ULL;

    const float* fmb = fm + (size_t)bb * (C_IN * HW_IN * HW_IN);
    const int rv0 = half ? 0 : 2;    // first valid window row
    const int rg0 = half ? 30 : 0;   // its global image row

    // per-thread A staging coords: u = it*256+tid (u<544), i=u>>4, q=u&15
    const int i0 = tid >> 4;
    const int i1 = 16 + i0;
    const int i2 = 32 + i0;
    const int q0 = tid & 15;
    const bool v2 = (tid < 32);      // 512+tid < 544

    f32x4 acc[4][4];
    #pragma unroll
    for (int mi = 0; mi < 4; ++mi)
        #pragma unroll
        for (int ni = 0; ni < 4; ++ni)
            acc[mi][ni] = (f32x4){0.f, 0.f, 0.f, 0.f};

    struct ASet { f32x4 x0, x1, x2; };
    struct BSet { bf16x8 b0, b1, b2, b3, b4, b5, b6, b7; };  // [ni*2+kk]
    ASet SA, SB;
    BSet B0, B1;

    // B base: row n = ntile*128 + wc*64 + ni*16 + l15, k-off = c*64 + kk*32 + l4*8
    const ushort* wbase = Wb + (size_t)(ntile * 128 + wc * 64 + l15) * K_TOT + l4 * 8;

    auto loadA = [&](int c, ASet& s) {
        const float* fmc = fmb + c * (HW_IN * HW_IN);
        s.x0 = *(const f32x4*)(fmc + (rg0 + i0) * 64 + q0 * 4);
        s.x1 = *(const f32x4*)(fmc + (rg0 + i1) * 64 + q0 * 4);
        if (v2) s.x2 = *(const f32x4*)(fmc + (rg0 + i2) * 64 + q0 * 4);
    };
    auto loadB = [&](int c, BSet& s) {
        const ushort* p = wbase + c * 64;
        s.b0 = *(const bf16x8*)(p);
        s.b1 = *(const bf16x8*)(p + 32);
        s.b2 = *(const bf16x8*)(p + 16 * K_TOT);
        s.b3 = *(const bf16x8*)(p + 16 * K_TOT + 32);
        s.b4 = *(const bf16x8*)(p + 32 * K_TOT);
        s.b5 = *(const bf16x8*)(p + 32 * K_TOT + 32);
        s.b6 = *(const bf16x8*)(p + 48 * K_TOT);
        s.b7 = *(const bf16x8*)(p + 48 * K_TOT + 32);
    };
    auto storeA = [&](const ASet& s, int buf) {
        uint* A32 = (uint*)As[buf];
        // interior col' = 2+4q -> uint index 36*r + 1 + 2q (4B-aligned b32 writes)
        int d0 = 36 * (rv0 + i0) + 1 + 2 * q0;
        A32[d0] = pk2(s.x0[0], s.x0[1]); A32[d0 + 1] = pk2(s.x0[2], s.x0[3]);
        int d1 = 36 * (rv0 + i1) + 1 + 2 * q0;
        A32[d1] = pk2(s.x1[0], s.x1[1]); A32[d1 + 1] = pk2(s.x1[2], s.x1[3]);
        if (v2) {
            int d2 = 36 * (rv0 + i2) + 1 + 2 * q0;
            A32[d2] = pk2(s.x2[0], s.x2[1]); A32[d2 + 1] = pk2(s.x2[2], s.x2[3]);
        }
    };
    auto compute = [&](int buf, const BSet& bs) {
        const ushort* A = As[buf];
        const bf16x8* bp[8] = {&bs.b0, &bs.b1, &bs.b2, &bs.b3,
                               &bs.b4, &bs.b5, &bs.b6, &bs.b7};
        #pragma unroll
        for (int kk = 0; kk < 2; ++kk) {
            bf16x8 a[4];
            #pragma unroll
            for (int mi = 0; mi < 4; ++mi) {
                int r = (wr * 4 + mi) * 4 + kk * 4 + l4;   // window row = ty*4 + ky
                const ushort* ap = A + r * ASTR + l15 * 4; // 8 contiguous bf16
                s16x4 lo = *(const s16x4*)ap;
                s16x4 hi = *(const s16x4*)(ap + 4);
                a[mi] = (bf16x8){lo[0], lo[1], lo[2], lo[3], hi[0], hi[1], hi[2], hi[3]};
            }
            #pragma unroll
            for (int mi = 0; mi < 4; ++mi)
                #pragma unroll
                for (int ni = 0; ni < 4; ++ni)
                    acc[mi][ni] = __builtin_amdgcn_mfma_f32_16x16x32_bf16(
                        a[mi], *bp[ni * 2 + kk], acc[mi][ni], 0, 0, 0);
        }
    };

    // ---- prologue
    __syncthreads();                 // zero-init visible
    loadA(0, SA);
    loadA(1, SB);
    loadB(0, B0);
    storeA(SA, 0);                   // waits only SA (SB/B0 stay in flight)
    __syncthreads();

    // ---- main loop, stride 2
    for (int c = 0; c < 64; c += 2) {
        if (c + 2 < 64) loadA(c + 2, SA);
        loadB(c + 1, B1);                     // c+1 <= 63 always
        compute(0, B0);                       // ch c
        storeA(SB, 1);                        // ch c+1 A commit
        __syncthreads();

        if (c + 3 < 64) loadA(c + 3, SB);
        if (c + 2 < 64) loadB(c + 2, B0);
        compute(1, B1);                       // ch c+1
        if (c + 2 < 64) storeA(SA, 0);        // ch c+2
        __syncthreads();
    }

    // ---- epilogue: + bias + pos_encoding
    const float L2_1E4_DIV128 = 0.10381025296523007f;  // log2(10000)/128
    const int mbase = mtile * 128 + wr * 64;
    const int tb    = half * 128 + wr * 64;
    #pragma unroll
    for (int ni = 0; ni < 4; ++ni) {
        const int d    = ntile * 128 + wc * 64 + ni * 16 + l15;
        const float bv = bias[d];
        const int dd   = d & 255;
        const int fi   = dd & 127;
        const float invf   = exp2f(-L2_1E4_DIV128 * (float)fi);
        const bool use_sin = (dd < 128);
        const bool use_x   = (d < 256);
        #pragma unroll
        for (int mi = 0; mi < 4; ++mi) {
            #pragma unroll
            for (int j = 0; j < 4; ++j) {
                int tm = mi * 16 + l4 * 4 + j;
                int t  = tb + tm;
                int p  = use_x ? (t & 15) : (t >> 4);
                float arg = (float)p * invf;
                float pe  = use_sin ? __sinf(arg) : __cosf(arg);
                out[(size_t)(mbase + tm) * D_OUT + d] = acc[mi][ni][j] + bv + pe;
            }
        }
    }
}

extern "C" void kernel_launch(void* const* d_in, const int* in_sizes, int n_in,
                              void* d_out, int out_size, void* d_ws, size_t ws_size,
                              hipStream_t stream) {
    const float* fm   = (const float*)d_in[0];
    const float* W    = (const float*)d_in[1];
    const float* bias = (const float*)d_in[2];
    float* out = (float*)d_out;
    ushort* Wb = (ushort*)d_ws;   // 512*4096*2 = 4 MB

    wcvt_kernel<<<(D_OUT * K_TOT / 4 + 255) / 256, 256, 0, stream>>>(W, Wb);
    tok_gemm<<<512, 256, 0, stream>>>(fm, Wb, bias, out);
}

// Round 8
// 164.058 us; speedup vs baseline: 1.3566x; 1.3566x over previous
//
#include <hip/hip_runtime.h>
#include <hip/hip_bf16.h>

typedef __attribute__((ext_vector_type(4))) float f32x4;
typedef __attribute__((ext_vector_type(8))) short bf16x8;
typedef __attribute__((ext_vector_type(4))) short s16x4;

#define C_IN   64
#define HW_IN  64
#define D_OUT  512
#define K_TOT  4096

// A window: 36 rows x 72 (stride) bf16; valid interior cols 2..65, rest zero.
#define AROWS 36
#define ASTR  72

__device__ __forceinline__ short f2bf(float x) {
    __hip_bfloat16 h = __float2bfloat16(x);
    return __builtin_bit_cast(short, h);
}
__device__ __forceinline__ uint pk2(float a, float b) {
    return (uint)(ushort)f2bf(a) | ((uint)(ushort)f2bf(b) << 16);
}
__device__ __forceinline__ void glds16(const ushort* g, ushort* l) {
    __builtin_amdgcn_global_load_lds(
        (const __attribute__((address_space(1))) uint*)g,
        (__attribute__((address_space(3))) uint*)l, 16, 0, 0);
}

// ---------------- kernel 0: W f32 -> bf16 (N x K row-major) ----------------
__global__ void wcvt_kernel(const float* __restrict__ W, ushort* __restrict__ Wb) {
    int i = (blockIdx.x * 256 + threadIdx.x) * 4;
    if (i < D_OUT * K_TOT) {
        f32x4 v = *(const f32x4*)(W + i);
        s16x4 o;
        o[0] = f2bf(v[0]); o[1] = f2bf(v[1]); o[2] = f2bf(v[2]); o[3] = f2bf(v[3]);
        *(s16x4*)(Wb + i) = o;
    }
}

// ---------------- kernel 1: implicit-GEMM conv + bias + pos-enc ----------------
// Grid: 512 = 128 M-tiles (BM=128 tokens) x 4 N-tiles (BN=128 of D).
// Block: 256 threads = 4 waves (2x2), each wave a 64x64 sub-tile.
// A: f32 global -> bf16 LDS (depth-2 register prefetch, dbuf).
// B: global_load_lds width-16 into LINEAR [128][64] LDS, XOR-swizzled via the
//    SOURCE address (slot s of row r holds W[r][8*(s^(r&7))]); reads unswizzle.
// Natural blockIdx mapping: same-mtile blocks land on the same XCD (measured).
__global__ __launch_bounds__(256) void tok_gemm(
    const float* __restrict__ fm,     // (64, 64, 64, 64) f32
    const ushort* __restrict__ Wb,    // (512, 4096) bf16
    const float* __restrict__ bias,   // (512)
    float* __restrict__ out)          // (64, 256, 512) f32
{
    __shared__ __align__(16) ushort As[2][AROWS * ASTR];   // bf16 channel window
    __shared__ __align__(16) ushort Bs[2][128 * 64];       // bf16 W tile, linear

    const int bid   = blockIdx.x;
    const int mtile = bid & 127;
    const int ntile = bid >> 7;

    const int bb   = mtile >> 1;     // batch image
    const int half = mtile & 1;      // top/bottom 8 token rows

    const int tid  = threadIdx.x;
    const int lane = tid & 63;
    const int wid  = tid >> 6;
    const int wr   = wid >> 1;
    const int wc   = wid & 1;
    const int l15  = lane & 15;
    const int l4   = lane >> 4;

    // ---- zero-init A buffers once (pad cols + invalid rows stay 0 forever)
    for (int i = tid; i < 2 * AROWS * ASTR / 4; i += 256)
        ((unsigned long long*)As)[i] = 0ULL;

    const float* fmb = fm + (size_t)bb * (C_IN * HW_IN * HW_IN);
    const int rv0 = half ? 0 : 2;    // first valid window row
    const int rg0 = half ? 30 : 0;   // its global image row

    // per-thread A staging coords
    const int i0 = tid >> 4;
    const int i1 = 16 + i0;
    const int i2 = 32 + i0;
    const int q0 = tid & 15;
    const bool v2 = (tid < 32);      // 512+tid < 544

    // ---- B async staging: wave w stages rows w*32..w*32+31 (4 instrs/wave).
    // per-lane global src: row = w*32 + it*8 + (lane>>3), k-slot swizzled.
    const int brow0 = wid * 32 + (lane >> 3);
    const int bswz  = ((lane & 7) ^ (lane >> 3)) * 8;   // ushort offset
    const ushort* bglob = Wb + (size_t)(ntile * 128 + brow0) * K_TOT + bswz;

    f32x4 acc[4][4];
    #pragma unroll
    for (int mi = 0; mi < 4; ++mi)
        #pragma unroll
        for (int ni = 0; ni < 4; ++ni)
            acc[mi][ni] = (f32x4){0.f, 0.f, 0.f, 0.f};

    struct ASet { f32x4 x0, x1, x2; };
    ASet SA, SB;

    auto loadA = [&](int c, ASet& s) {
        const float* fmc = fmb + c * (HW_IN * HW_IN);
        s.x0 = *(const f32x4*)(fmc + (rg0 + i0) * 64 + q0 * 4);
        s.x1 = *(const f32x4*)(fmc + (rg0 + i1) * 64 + q0 * 4);
        if (v2) s.x2 = *(const f32x4*)(fmc + (rg0 + i2) * 64 + q0 * 4);
    };
    auto storeA = [&](const ASet& s, int buf) {
        uint* A32 = (uint*)As[buf];
        int d0 = 36 * (rv0 + i0) + 1 + 2 * q0;
        A32[d0] = pk2(s.x0[0], s.x0[1]); A32[d0 + 1] = pk2(s.x0[2], s.x0[3]);
        int d1 = 36 * (rv0 + i1) + 1 + 2 * q0;
        A32[d1] = pk2(s.x1[0], s.x1[1]); A32[d1 + 1] = pk2(s.x1[2], s.x1[3]);
        if (v2) {
            int d2 = 36 * (rv0 + i2) + 1 + 2 * q0;
            A32[d2] = pk2(s.x2[0], s.x2[1]); A32[d2 + 1] = pk2(s.x2[2], s.x2[3]);
        }
    };
    auto issueB = [&](int c, int buf) {
        const ushort* g = bglob + c * 64;
        ushort* l = &Bs[buf][wid * 4 * 512 + (lane & 7)];  // base is wave-uniform
        #pragma unroll
        for (int it = 0; it < 4; ++it)
            glds16(g + (size_t)it * 8 * K_TOT, l + it * 512);
    };
    auto compute = [&](int buf) {
        const ushort* A = As[buf];
        const ushort* B = Bs[buf];
        #pragma unroll
        for (int kk = 0; kk < 2; ++kk) {
            bf16x8 a[4], b[4];
            #pragma unroll
            for (int mi = 0; mi < 4; ++mi) {
                int r = (wr * 4 + mi) * 4 + kk * 4 + l4;   // window row = oy*4 + ky
                const ushort* ap = A + r * ASTR + l15 * 4; // 8 contiguous bf16 (kx)
                s16x4 lo = *(const s16x4*)ap;
                s16x4 hi = *(const s16x4*)(ap + 4);
                a[mi] = (bf16x8){lo[0], lo[1], lo[2], lo[3], hi[0], hi[1], hi[2], hi[3]};
            }
            #pragma unroll
            for (int ni = 0; ni < 4; ++ni) {
                int n = wc * 64 + ni * 16 + l15;
                int s = (kk * 4 + l4) ^ (l15 & 7);         // un-swizzle k-slot
                b[ni] = *(const bf16x8*)(B + n * 64 + s * 8);
            }
            #pragma unroll
            for (int mi = 0; mi < 4; ++mi)
                #pragma unroll
                for (int ni = 0; ni < 4; ++ni)
                    acc[mi][ni] = __builtin_amdgcn_mfma_f32_16x16x32_bf16(
                        a[mi], b[ni], acc[mi][ni], 0, 0, 0);
        }
    };

    // ---- prologue: stage ch0 (A depth-2, B async), one barrier
    loadA(0, SA);
    loadA(1, SB);
    issueB(0, 0);
    storeA(SA, 0);                   // waits only SA's loads
    __syncthreads();                 // drains B ch0 + makes As[0]/zeros visible

    // ---- main loop, stride 2: one barrier per channel
    for (int c = 0; c < 64; c += 2) {
        if (c + 2 < 64) loadA(c + 2, SA);
        issueB(c + 1, 1);                     // c+1 <= 63 always
        compute(0);                           // ch c
        storeA(SB, 1);                        // ch c+1 A commit
        __syncthreads();                      // drains B ch c+1

        if (c + 3 < 64) loadA(c + 3, SB);
        if (c + 2 < 64) issueB(c + 2, 0);
        compute(1);                           // ch c+1
        if (c + 2 < 64) storeA(SA, 0);        // ch c+2
        __syncthreads();
    }

    // ---- epilogue: + bias + pos_encoding
    const float L2_1E4_DIV128 = 0.10381025296523007f;  // log2(10000)/128
    const int mbase = mtile * 128 + wr * 64;
    const int tb    = half * 128 + wr * 64;
    #pragma unroll
    for (int ni = 0; ni < 4; ++ni) {
        const int d    = ntile * 128 + wc * 64 + ni * 16 + l15;
        const float bv = bias[d];
        const int dd   = d & 255;
        const int fi   = dd & 127;
        const float invf   = exp2f(-L2_1E4_DIV128 * (float)fi);
        const bool use_sin = (dd < 128);
        const bool use_x   = (d < 256);
        #pragma unroll
        for (int mi = 0; mi < 4; ++mi) {
            #pragma unroll
            for (int j = 0; j < 4; ++j) {
                int tm = mi * 16 + l4 * 4 + j;
                int t  = tb + tm;
                int p  = use_x ? (t & 15) : (t >> 4);
                float arg = (float)p * invf;
                float pe  = use_sin ? __sinf(arg) : __cosf(arg);
                out[(size_t)(mbase + tm) * D_OUT + d] = acc[mi][ni][j] + bv + pe;
            }
        }
    }
}

extern "C" void kernel_launch(void* const* d_in, const int* in_sizes, int n_in,
                              void* d_out, int out_size, void* d_ws, size_t ws_size,
                              hipStream_t stream) {
    const float* fm   = (const float*)d_in[0];
    const float* W    = (const float*)d_in[1];
    const float* bias = (const float*)d_in[2];
    float* out = (float*)d_out;
    ushort* Wb = (ushort*)d_ws;   // 512*4096*2 = 4 MB

    wcvt_kernel<<<(D_OUT * K_TOT / 4 + 255) / 256, 256, 0, stream>>>(W, Wb);
    tok_gemm<<<512, 256, 0, stream>>>(fm, Wb, bias, out);
}